// Round 12
// baseline (340.266 us; speedup 1.0000x reference)
//
#include <hip/hip_runtime.h>
#include <hip/hip_bf16.h>
#include <math.h>

// N=50000, E=500000, SED=128, HID=64, H=2, F_node=128
// Round 12: layer-2 aggregation/GEMM swapped (aggregate hmid with per-head
// alpha -> A[N,256]; zsd = A @ Wbig + bz, Wbig = 0.5*W2compose(fc2) precomputed;
// logits2 fused into agg1 epilogue via v2s/v2d). gemm2/h2pre/h2bf eliminated.
// agg2 gather volume halves (512B -> 256B per edge). 10 dispatches.

typedef short short8 __attribute__((ext_vector_type(8)));
typedef float floatx4 __attribute__((ext_vector_type(4)));
typedef float v2f __attribute__((ext_vector_type(2)));
typedef unsigned uint2v __attribute__((ext_vector_type(2)));

__device__ __forceinline__ v2f bfpair(unsigned v) {
    uint2v t; t.x = v << 16; t.y = v & 0xFFFF0000u;
    return __builtin_bit_cast(v2f, t);
}
__device__ __forceinline__ unsigned short bfbits(float f) {
    return __builtin_bit_cast(unsigned short, __float2bfloat16(f));
}
__device__ __forceinline__ unsigned packbf(float a, float b) {
    return ((unsigned)bfbits(b) << 16) | (unsigned)bfbits(a);
}
__device__ __forceinline__ float lrelu(float v) { return v > 0.f ? v : 0.2f * v; }

// ---- prep: counts zero; c1; w1frag; Wbig frag (W2∘fc2); v2s/v2d; bz ----
__global__ void prep_kernel(const float* __restrict__ cls, const float* __restrict__ fc0_w,
                            const float* __restrict__ fc0_b, const float* __restrict__ W1,
                            const float* __restrict__ W2, const float* __restrict__ fc2_w,
                            const float* __restrict__ fc2_b, const float* __restrict__ bias2,
                            const float* __restrict__ att_s2, const float* __restrict__ att_d2,
                            float* __restrict__ c1,
                            __hip_bfloat16* __restrict__ w1frag,
                            __hip_bfloat16* __restrict__ wbigfrag,
                            float* __restrict__ v2s, float* __restrict__ v2d,
                            float* __restrict__ bz,
                            int* __restrict__ counts, int N) {
    int tid = threadIdx.x;
    int gstride = gridDim.x * blockDim.x;
    int g = blockIdx.x * blockDim.x + tid;
    for (int i = g; i < N; i += gstride) counts[i] = 0;
    if (blockIdx.x == 0) {
        __shared__ float s_sent[128];
        if (tid < 128) {
            float acc = fc0_b[tid];
            const float* row = fc0_w + (size_t)tid * 768;
            for (int k = 0; k < 768; ++k) acc += row[k] * cls[k];
            s_sent[tid] = acc;
        }
        __syncthreads();
        if (tid < 128) {
            float acc = 0.f;
            for (int k = 0; k < 128; ++k) acc += s_sent[k] * W1[(128 + k) * 128 + tid];
            c1[tid] = acc;
        }
    }
    // w1frag: B[k][n], k=kt*32+(l>>4)*8+j (KT=4), n=nt*16+(l&15) (NT=8)
    for (int i = g; i < 16384; i += gstride) {
        int j = i & 7, l = (i >> 3) & 63, nt = (i >> 9) & 7, kt = (i >> 12) & 3;
        int k = kt * 32 + (l >> 4) * 8 + j;
        int n = nt * 16 + (l & 15);
        w1frag[i] = __float2bfloat16(W1[k * 128 + n]);
    }
    // Wbig frag: K=256 (k=h*128+k' over A=[A0|A1]), NT=16 (n<128 zs, n>=128 zd)
    // Wbig[k][n] = 0.5 * sum_{c'} W2[k'][h*128+c'] * fc2row(n)[c']
    for (int i = g; i < 65536; i += gstride) {
        int j = i & 7, l = (i >> 3) & 63, nt = (i >> 9) & 15, kt = (i >> 13) & 7;
        int k = kt * 32 + (l >> 4) * 8 + j;
        int n = nt * 16 + (l & 15);
        int h = k >> 7, kp = k & 127;
        const float* w2row = W2 + (size_t)kp * 256 + h * 128;
        const float* fcrow = (n < 128) ? (fc2_w + (size_t)n * 256)
                                       : (fc2_w + (size_t)(n - 128) * 256 + 128);
        float acc = 0.f;
        for (int c2 = 0; c2 < 128; ++c2) acc += w2row[c2] * fcrow[c2];
        wbigfrag[i] = __float2bfloat16(0.5f * acc);
    }
    // v2s/v2d [h*128+k']: logits2 vectors  a_s2[n][h] = hmid[n] . v2s[h]
    for (int i = g; i < 256; i += gstride) {
        int h = i >> 7, kp = i & 127;
        const float* w2row = W2 + (size_t)kp * 256 + h * 128;
        const float* as = att_s2 + h * 128;
        const float* ad = att_d2 + h * 128;
        float s = 0.f, dd = 0.f;
        for (int c = 0; c < 128; ++c) { s += w2row[c] * as[c]; dd += w2row[c] * ad[c]; }
        v2s[i] = s; v2d[i] = dd;
    }
    // bz[256]: bias2 pushed through fc2 (+fc2_b on zd half)
    for (int i = g; i < 256; i += gstride) {
        const float* fcrow = (i < 128) ? (fc2_w + (size_t)i * 256)
                                       : (fc2_w + (size_t)(i - 128) * 256 + 128);
        float acc = 0.f;
        for (int c = 0; c < 128; ++c) acc += bias2[c] * fcrow[c];
        if (i >= 128) acc += fc2_b[i - 128];
        bz[i] = acc;
    }
}

// ---- CSR scan (hierarchical) ----
__global__ void __launch_bounds__(256) bsum_kernel(const int* __restrict__ counts,
                                                   int* __restrict__ bsum, int N) {
    int base = blockIdx.x * 1024;
    int tid = threadIdx.x;
    int v = 0;
    #pragma unroll
    for (int k = 0; k < 4; ++k) {
        int idx = base + k * 256 + tid;
        if (idx < N) v += counts[idx];
    }
    #pragma unroll
    for (int off = 1; off < 64; off <<= 1) v += __shfl_xor(v, off, 64);
    __shared__ int ws[4];
    if ((tid & 63) == 0) ws[tid >> 6] = v;
    __syncthreads();
    if (tid == 0) bsum[blockIdx.x] = ws[0] + ws[1] + ws[2] + ws[3];
}

__global__ void top_scan_kernel(const int* __restrict__ bsum, int* __restrict__ boff, int nb) {
    int lane = threadIdx.x;
    int v = (lane < nb) ? bsum[lane] : 0;
    int x = v;
    #pragma unroll
    for (int off = 1; off < 64; off <<= 1) {
        int t = __shfl_up(x, off, 64);
        if (lane >= off) x += t;
    }
    if (lane < nb) boff[lane] = x - v;
}

__global__ void __launch_bounds__(1024) local_scan_kernel(const int* __restrict__ counts,
                                                          const int* __restrict__ boff,
                                                          int* __restrict__ row, int* __restrict__ woff,
                                                          int N, int E) {
    int tid = threadIdx.x, lane = tid & 63, wv = tid >> 6;
    int base = blockIdx.x * 1024;
    __shared__ int wsum[16];
    int v = (base + tid < N) ? counts[base + tid] : 0;
    int x = v;
    #pragma unroll
    for (int off = 1; off < 64; off <<= 1) {
        int t = __shfl_up(x, off, 64);
        if (lane >= off) x += t;
    }
    if (lane == 63) wsum[wv] = x;
    __syncthreads();
    if (wv == 0 && lane < 16) {
        int y = wsum[lane];
        #pragma unroll
        for (int off = 1; off < 16; off <<= 1) {
            int t = __shfl_up(y, off, 64);
            if (lane >= off) y += t;
        }
        wsum[lane] = y;
    }
    __syncthreads();
    int excl = boff[blockIdx.x] + (wv ? wsum[wv - 1] : 0) + x - v;
    if (base + tid < N) { row[base + tid] = excl; woff[base + tid] = excl; }
    if (blockIdx.x == 0 && tid == 0) row[N] = E;
}

__global__ void scatter_kernel(const int* __restrict__ src, const int* __restrict__ dst,
                               int* __restrict__ woff, int* __restrict__ srcs, int E) {
    int e = blockIdx.x * blockDim.x + threadIdx.x;
    if (e < E) {
        int pos = atomicAdd(&woff[dst[e]], 1);
        srcs[pos] = src[e];
    }
}

// ---- gemm1 MFMA + fused degree count ----
__global__ void __launch_bounds__(256) gemm1_count_kernel(
        const float* __restrict__ x, const __hip_bfloat16* __restrict__ wfrag,
        const float* __restrict__ c1, const float* __restrict__ att_s, const float* __restrict__ att_d,
        __hip_bfloat16* __restrict__ h1bf, float* __restrict__ a_src, float* __restrict__ a_dst,
        const int* __restrict__ dst, int* __restrict__ counts, int E, int G1, int N) {
    if ((int)blockIdx.x >= G1) {
        int e = ((int)blockIdx.x - G1) * 256 + threadIdx.x;
        if (e < E) atomicAdd(&counts[dst[e]], 1);
        return;
    }
    int lane = threadIdx.x & 63, wv = threadIdx.x >> 6;
    int lo = lane & 15, quad = lane >> 4;
    int rowbase = ((int)blockIdx.x * 4 + wv) * 16;
    if (rowbase >= N) return;
    int arow = rowbase + lo; if (arow >= N) arow = N - 1;
    const float* ap = x + (size_t)arow * 128 + quad * 8;
    floatx4 acc[8];
    #pragma unroll
    for (int nt = 0; nt < 8; ++nt) acc[nt] = (floatx4){0.f, 0.f, 0.f, 0.f};
    const short8* bf = (const short8*)wfrag;
    #pragma unroll
    for (int kt = 0; kt < 4; ++kt) {
        float4 fa = *(const float4*)(ap + kt * 32);
        float4 fb = *(const float4*)(ap + kt * 32 + 4);
        short8 a;
        a[0] = (short)bfbits(fa.x); a[1] = (short)bfbits(fa.y);
        a[2] = (short)bfbits(fa.z); a[3] = (short)bfbits(fa.w);
        a[4] = (short)bfbits(fb.x); a[5] = (short)bfbits(fb.y);
        a[6] = (short)bfbits(fb.z); a[7] = (short)bfbits(fb.w);
        #pragma unroll
        for (int nt = 0; nt < 8; ++nt)
            acc[nt] = __builtin_amdgcn_mfma_f32_16x16x32_bf16(a, bf[(kt * 8 + nt) * 64 + lane], acc[nt], 0, 0, 0);
    }
    float ps0[4] = {0,0,0,0}, ps1[4] = {0,0,0,0}, pd0[4] = {0,0,0,0}, pd1[4] = {0,0,0,0};
    #pragma unroll
    for (int nt = 0; nt < 8; ++nt) {
        int ch = nt * 16 + lo;
        float cv = c1[ch], as_v = att_s[ch], ad_v = att_d[ch];
        #pragma unroll
        for (int r = 0; r < 4; ++r) {
            int row = rowbase + quad * 4 + r;
            float val = acc[nt][r] + cv;
            if (row < N) ((unsigned short*)h1bf)[(size_t)row * 128 + ch] = bfbits(val);
            if (nt < 4) { ps0[r] += val * as_v; pd0[r] += val * ad_v; }
            else        { ps1[r] += val * as_v; pd1[r] += val * ad_v; }
        }
    }
    #pragma unroll
    for (int r = 0; r < 4; ++r) {
        int row = rowbase + quad * 4 + r;
        float v0 = ps0[r], v1 = ps1[r], v2 = pd0[r], v3 = pd1[r];
        #pragma unroll
        for (int off = 1; off < 16; off <<= 1) {
            v0 += __shfl_xor(v0, off, 64); v1 += __shfl_xor(v1, off, 64);
            v2 += __shfl_xor(v2, off, 64); v3 += __shfl_xor(v3, off, 64);
        }
        if (lo == 0 && row < N) {
            a_src[row * 2 + 0] = v0; a_src[row * 2 + 1] = v1;
            a_dst[row * 2 + 0] = v2; a_dst[row * 2 + 1] = v3;
        }
    }
}

// ---- agg1: 16 lanes/dst; unroll-4; ELU -> hmid bf16; + fused logits2 ----
__global__ void __launch_bounds__(256) agg1_csr_kernel(
        const int* __restrict__ row, const int* __restrict__ srcs,
        const float* __restrict__ a_src, const float* __restrict__ a_dst,
        const unsigned* __restrict__ h1u, const float* __restrict__ bias1,
        const float* __restrict__ v2s, const float* __restrict__ v2d,
        unsigned* __restrict__ hmid_u, float* __restrict__ a_s2, float* __restrict__ a_d2, int N) {
    int tid = threadIdx.x;
    int d = blockIdx.x * 16 + (tid >> 4);
    if (d >= N) return;
    int q = tid & 15;
    int beg = row[d], end = row[d + 1];
    float2 adp = ((const float2*)a_dst)[d];
    float den0 = 0.f, den1 = 0.f;
    v2f facc2[4];
    #pragma unroll
    for (int m = 0; m < 4; ++m) facc2[m] = (v2f){0.f, 0.f};
    for (int i = beg; i < end; i += 4) {
        bool h1 = (i + 1) < end, h2 = (i + 2) < end, h3 = (i + 3) < end;
        int s0 = srcs[i];
        int s1 = h1 ? srcs[i + 1] : s0;
        int s2 = h2 ? srcs[i + 2] : s0;
        int s3 = h3 ? srcs[i + 3] : s0;
        float2 as0 = ((const float2*)a_src)[s0];
        float2 as1 = ((const float2*)a_src)[s1];
        float2 as2 = ((const float2*)a_src)[s2];
        float2 as3 = ((const float2*)a_src)[s3];
        uint4 u0 = ((const uint4*)(h1u + (size_t)s0 * 64))[q];
        uint4 u1 = ((const uint4*)(h1u + (size_t)s1 * 64))[q];
        uint4 u2 = ((const uint4*)(h1u + (size_t)s2 * 64))[q];
        uint4 u3 = ((const uint4*)(h1u + (size_t)s3 * 64))[q];
        float e00 = __expf(lrelu(as0.x + adp.x));
        float e01 = __expf(lrelu(as0.y + adp.y));
        float e10 = h1 ? __expf(lrelu(as1.x + adp.x)) : 0.f;
        float e11 = h1 ? __expf(lrelu(as1.y + adp.y)) : 0.f;
        float e20 = h2 ? __expf(lrelu(as2.x + adp.x)) : 0.f;
        float e21 = h2 ? __expf(lrelu(as2.y + adp.y)) : 0.f;
        float e30 = h3 ? __expf(lrelu(as3.x + adp.x)) : 0.f;
        float e31 = h3 ? __expf(lrelu(as3.y + adp.y)) : 0.f;
        den0 += e00 + e10 + e20 + e30;
        den1 += e01 + e11 + e21 + e31;
        float w0 = (q < 8) ? e00 : e01;
        float w1 = (q < 8) ? e10 : e11;
        float w2 = (q < 8) ? e20 : e21;
        float w3 = (q < 8) ? e30 : e31;
        facc2[0] += bfpair(u0.x) * w0 + bfpair(u1.x) * w1 + bfpair(u2.x) * w2 + bfpair(u3.x) * w3;
        facc2[1] += bfpair(u0.y) * w0 + bfpair(u1.y) * w1 + bfpair(u2.y) * w2 + bfpair(u3.y) * w3;
        facc2[2] += bfpair(u0.z) * w0 + bfpair(u1.z) * w1 + bfpair(u2.z) * w2 + bfpair(u3.z) * w3;
        facc2[3] += bfpair(u0.w) * w0 + bfpair(u1.w) * w1 + bfpair(u2.w) * w2 + bfpair(u3.w) * w3;
    }
    float inv = 1.f / (((q < 8) ? den0 : den1) + 1e-16f);
    int c0 = 8 * q;
    float v[8];
    #pragma unroll
    for (int m = 0; m < 4; ++m) {
        float va = facc2[m].x * inv + bias1[c0 + 2 * m];
        float vb = facc2[m].y * inv + bias1[c0 + 2 * m + 1];
        v[2 * m]     = va > 0.f ? va : expm1f(va);
        v[2 * m + 1] = vb > 0.f ? vb : expm1f(vb);
    }
    uint4 o;
    o.x = packbf(v[0], v[1]); o.y = packbf(v[2], v[3]);
    o.z = packbf(v[4], v[5]); o.w = packbf(v[6], v[7]);
    ((uint4*)(hmid_u + (size_t)d * 64))[q] = o;
    // fused logits2: a_s2[d][h] = hmid[d] . v2s[h] ; reduce over 16-lane group
    float s20 = 0.f, s21 = 0.f, d20 = 0.f, d21 = 0.f;
    #pragma unroll
    for (int m = 0; m < 8; ++m) {
        float hv = v[m];
        s20 += hv * v2s[c0 + m];
        s21 += hv * v2s[128 + c0 + m];
        d20 += hv * v2d[c0 + m];
        d21 += hv * v2d[128 + c0 + m];
    }
    #pragma unroll
    for (int off = 1; off < 16; off <<= 1) {
        s20 += __shfl_xor(s20, off, 64); s21 += __shfl_xor(s21, off, 64);
        d20 += __shfl_xor(d20, off, 64); d21 += __shfl_xor(d21, off, 64);
    }
    if (q == 0) {
        ((float2*)a_s2)[d] = make_float2(s20, s21);
        ((float2*)a_d2)[d] = make_float2(d20, d21);
    }
}

// ---- agg2m: 16 lanes/dst; gather hmid (256B); dual-head accumulate -> Acat ----
__global__ void __launch_bounds__(256) agg2m_csr_kernel(
        const int* __restrict__ row, const int* __restrict__ srcs,
        const float* __restrict__ a_src, const float* __restrict__ a_dst,
        const unsigned* __restrict__ hmid_u, unsigned* __restrict__ Acat_u, int N) {
    int tid = threadIdx.x;
    int d = blockIdx.x * 16 + (tid >> 4);
    if (d >= N) return;
    int q = tid & 15;
    int beg = row[d], end = row[d + 1];
    float2 adp = ((const float2*)a_dst)[d];
    float den0 = 0.f, den1 = 0.f;
    v2f a0[4], a1[4];
    #pragma unroll
    for (int m = 0; m < 4; ++m) { a0[m] = (v2f){0.f, 0.f}; a1[m] = (v2f){0.f, 0.f}; }
    for (int i = beg; i < end; i += 4) {
        bool h1 = (i + 1) < end, h2 = (i + 2) < end, h3 = (i + 3) < end;
        int s0 = srcs[i];
        int s1 = h1 ? srcs[i + 1] : s0;
        int s2 = h2 ? srcs[i + 2] : s0;
        int s3 = h3 ? srcs[i + 3] : s0;
        float2 as0 = ((const float2*)a_src)[s0];
        float2 as1 = ((const float2*)a_src)[s1];
        float2 as2 = ((const float2*)a_src)[s2];
        float2 as3 = ((const float2*)a_src)[s3];
        uint4 u0 = ((const uint4*)(hmid_u + (size_t)s0 * 64))[q];
        uint4 u1 = ((const uint4*)(hmid_u + (size_t)s1 * 64))[q];
        uint4 u2 = ((const uint4*)(hmid_u + (size_t)s2 * 64))[q];
        uint4 u3 = ((const uint4*)(hmid_u + (size_t)s3 * 64))[q];
        float e00 = __expf(lrelu(as0.x + adp.x));
        float e01 = __expf(lrelu(as0.y + adp.y));
        float e10 = h1 ? __expf(lrelu(as1.x + adp.x)) : 0.f;
        float e11 = h1 ? __expf(lrelu(as1.y + adp.y)) : 0.f;
        float e20 = h2 ? __expf(lrelu(as2.x + adp.x)) : 0.f;
        float e21 = h2 ? __expf(lrelu(as2.y + adp.y)) : 0.f;
        float e30 = h3 ? __expf(lrelu(as3.x + adp.x)) : 0.f;
        float e31 = h3 ? __expf(lrelu(as3.y + adp.y)) : 0.f;
        den0 += e00 + e10 + e20 + e30;
        den1 += e01 + e11 + e21 + e31;
        v2f p0x = bfpair(u0.x), p0y = bfpair(u0.y), p0z = bfpair(u0.z), p0w = bfpair(u0.w);
        v2f p1x = bfpair(u1.x), p1y = bfpair(u1.y), p1z = bfpair(u1.z), p1w = bfpair(u1.w);
        v2f p2x = bfpair(u2.x), p2y = bfpair(u2.y), p2z = bfpair(u2.z), p2w = bfpair(u2.w);
        v2f p3x = bfpair(u3.x), p3y = bfpair(u3.y), p3z = bfpair(u3.z), p3w = bfpair(u3.w);
        a0[0] += p0x * e00 + p1x * e10 + p2x * e20 + p3x * e30;
        a0[1] += p0y * e00 + p1y * e10 + p2y * e20 + p3y * e30;
        a0[2] += p0z * e00 + p1z * e10 + p2z * e20 + p3z * e30;
        a0[3] += p0w * e00 + p1w * e10 + p2w * e20 + p3w * e30;
        a1[0] += p0x * e01 + p1x * e11 + p2x * e21 + p3x * e31;
        a1[1] += p0y * e01 + p1y * e11 + p2y * e21 + p3y * e31;
        a1[2] += p0z * e01 + p1z * e11 + p2z * e21 + p3z * e31;
        a1[3] += p0w * e01 + p1w * e11 + p2w * e21 + p3w * e31;
    }
    float inv0 = 1.f / (den0 + 1e-16f);
    float inv1 = 1.f / (den1 + 1e-16f);
    uint4 o0, o1;
    o0.x = packbf(a0[0].x * inv0, a0[0].y * inv0);
    o0.y = packbf(a0[1].x * inv0, a0[1].y * inv0);
    o0.z = packbf(a0[2].x * inv0, a0[2].y * inv0);
    o0.w = packbf(a0[3].x * inv0, a0[3].y * inv0);
    o1.x = packbf(a1[0].x * inv1, a1[0].y * inv1);
    o1.y = packbf(a1[1].x * inv1, a1[1].y * inv1);
    o1.z = packbf(a1[2].x * inv1, a1[2].y * inv1);
    o1.w = packbf(a1[3].x * inv1, a1[3].y * inv1);
    uint4* orow = (uint4*)(Acat_u + (size_t)d * 128);
    orow[q] = o0;        // head-0 half: channels k' = 8q..8q+7
    orow[16 + q] = o1;   // head-1 half
}

// ---- zsd MFMA: zsd[N,256](bf16) = Acat[N,256] @ Wbigfrag + bz ----
__global__ void __launch_bounds__(256) zsd_mfma_kernel(
        const __hip_bfloat16* __restrict__ Acat, const __hip_bfloat16* __restrict__ wfrag,
        const float* __restrict__ bz, __hip_bfloat16* __restrict__ zsd, int N) {
    int lane = threadIdx.x & 63, wv = threadIdx.x >> 6;
    int lo = lane & 15, quad = lane >> 4;
    int rowbase = (blockIdx.x * 4 + wv) * 16;
    if (rowbase >= N) return;
    int arow = rowbase + lo; if (arow >= N) arow = N - 1;
    const __hip_bfloat16* ap = Acat + (size_t)arow * 256 + quad * 8;
    floatx4 acc[16];
    #pragma unroll
    for (int nt = 0; nt < 16; ++nt) acc[nt] = (floatx4){0.f, 0.f, 0.f, 0.f};
    const short8* bf = (const short8*)wfrag;
    #pragma unroll
    for (int kt = 0; kt < 8; ++kt) {
        short8 a = *(const short8*)(ap + kt * 32);
        #pragma unroll
        for (int nt = 0; nt < 16; ++nt)
            acc[nt] = __builtin_amdgcn_mfma_f32_16x16x32_bf16(a, bf[(kt * 16 + nt) * 64 + lane], acc[nt], 0, 0, 0);
    }
    #pragma unroll
    for (int nt = 0; nt < 16; ++nt) {
        int ch = nt * 16 + lo;
        float bv = bz[ch];
        #pragma unroll
        for (int r = 0; r < 4; ++r) {
            int row = rowbase + quad * 4 + r;
            if (row < N) ((unsigned short*)zsd)[(size_t)row * 256 + ch] = bfbits(acc[nt][r] + bv);
        }
    }
}

// ---- edge head: batched gathers (8 rounds), channel-split, shfl_xor(16) add ----
__global__ void __launch_bounds__(256) edge_zsd_kernel(
        const int* __restrict__ src, const int* __restrict__ dst,
        const unsigned* __restrict__ zsd_u, const float* __restrict__ fc3_w,
        const float* __restrict__ fc3_b, float* __restrict__ out, int E) {
    int lane = threadIdx.x & 63, wv = threadIdx.x >> 6;
    int g = lane >> 5, r = (lane >> 4) & 1, q = lane & 15;
    int base = (blockIdx.x * 4 + wv) * 16;
    if (base >= E) return;
    v2f f30 = {fc3_w[8 * q + 4 * r + 0], fc3_w[8 * q + 4 * r + 1]};
    v2f f31 = {fc3_w[8 * q + 4 * r + 2], fc3_w[8 * q + 4 * r + 3]};
    float b3 = fc3_b[0];
    int nodes[8];
    #pragma unroll
    for (int j = 0; j < 8; ++j) {
        int e = base + 2 * j + g;
        int ec = e < E ? e : E - 1;
        nodes[j] = r ? dst[ec] : src[ec];
    }
    uint4 rows[8];
    #pragma unroll
    for (int j = 0; j < 8; ++j)
        rows[j] = ((const uint4*)(zsd_u + (size_t)nodes[j] * 128 + (r << 6)))[q];
    #pragma unroll
    for (int j = 0; j < 8; ++j) {
        uint4 mine = rows[j];
        unsigned sx = (unsigned)__shfl_xor((int)mine.x, 16, 64);
        unsigned sy = (unsigned)__shfl_xor((int)mine.y, 16, 64);
        unsigned sz = (unsigned)__shfl_xor((int)mine.z, 16, 64);
        unsigned sw = (unsigned)__shfl_xor((int)mine.w, 16, 64);
        unsigned mA = r ? mine.z : mine.x;
        unsigned mB = r ? mine.w : mine.y;
        unsigned oA = r ? sz : sx;
        unsigned oB = r ? sw : sy;
        v2f sA = bfpair(mA) + bfpair(oA);
        v2f sB = bfpair(mB) + bfpair(oB);
        sA.x = fmaxf(sA.x, 0.f); sA.y = fmaxf(sA.y, 0.f);
        sB.x = fmaxf(sB.x, 0.f); sB.y = fmaxf(sB.y, 0.f);
        v2f p2 = sA * f30 + sB * f31;
        float p = p2.x + p2.y;
        #pragma unroll
        for (int off = 1; off < 32; off <<= 1) p += __shfl_xor(p, off, 64);
        int e = base + 2 * j + g;
        if ((lane & 31) == 0 && e < E)
            out[e] = 1.f / (1.f + expf(-(p + b3)));
    }
}

extern "C" void kernel_launch(void* const* d_in, const int* in_sizes, int n_in,
                              void* d_out, int out_size, void* d_ws, size_t ws_size,
                              hipStream_t stream) {
    const float* x      = (const float*)d_in[0];
    const int*   ei     = (const int*)d_in[1];
    const float* cls    = (const float*)d_in[2];
    const float* fc0_w  = (const float*)d_in[3];
    const float* fc0_b  = (const float*)d_in[4];
    const float* W1     = (const float*)d_in[5];
    const float* att_s1 = (const float*)d_in[6];
    const float* att_d1 = (const float*)d_in[7];
    const float* bias1  = (const float*)d_in[8];
    const float* W2     = (const float*)d_in[9];
    const float* att_s2 = (const float*)d_in[10];
    const float* att_d2 = (const float*)d_in[11];
    const float* bias2  = (const float*)d_in[12];
    const float* fc2_w  = (const float*)d_in[13];
    const float* fc2_b  = (const float*)d_in[14];
    const float* fc3_w  = (const float*)d_in[15];
    const float* fc3_b  = (const float*)d_in[16];
    float* out = (float*)d_out;

    int N = in_sizes[0] / 128;
    int E = in_sizes[1] / 2;
    const int* src = ei;
    const int* dst = ei + E;
    int nb = (N + 1023) / 1024;

    float* w = (float*)d_ws;
    size_t off = 0;
    auto alloc = [&](size_t n) { float* p = w + off; off += (n + 63) & ~(size_t)63; return p; };
    float* c1       = alloc(128);
    float* w1fragf  = alloc(16384 / 2);
    float* wbigf    = alloc(65536 / 2);
    float* v2s      = alloc(256);
    float* v2d      = alloc(256);
    float* bz       = alloc(256);
    float* a_s1     = alloc((size_t)N * 2);
    float* a_d1     = alloc((size_t)N * 2);
    float* a_s2     = alloc((size_t)N * 2);
    float* a_d2     = alloc((size_t)N * 2);
    float* h1bff    = alloc((size_t)N * 64);   // N*128 bf16
    float* hmidf    = alloc((size_t)N * 64);   // N*128 bf16
    float* Acatf    = alloc((size_t)N * 128);  // N*256 bf16
    float* zsdf     = alloc((size_t)N * 128);  // N*256 bf16
    int* counts = (int*)alloc(N);
    int* rowp   = (int*)alloc(N + 1);
    int* woff   = (int*)alloc(N);
    int* srcs   = (int*)alloc(E);
    int* bsum   = (int*)alloc(64);
    int* boff   = (int*)alloc(64);
    __hip_bfloat16* w1frag   = (__hip_bfloat16*)w1fragf;
    __hip_bfloat16* wbigfrag = (__hip_bfloat16*)wbigf;
    __hip_bfloat16* h1bf     = (__hip_bfloat16*)h1bff;
    __hip_bfloat16* hmid     = (__hip_bfloat16*)hmidf;
    __hip_bfloat16* Acat     = (__hip_bfloat16*)Acatf;
    __hip_bfloat16* zsd      = (__hip_bfloat16*)zsdf;

    prep_kernel<<<64, 256, 0, stream>>>(cls, fc0_w, fc0_b, W1, W2, fc2_w, fc2_b, bias2,
                                        att_s2, att_d2, c1, w1frag, wbigfrag, v2s, v2d, bz,
                                        counts, N);
    int G1 = (N + 63) / 64;
    int G2 = (E + 255) / 256;
    gemm1_count_kernel<<<G1 + G2, 256, 0, stream>>>(x, w1frag, c1, att_s1, att_d1, h1bf, a_s1, a_d1,
                                                    dst, counts, E, G1, N);
    bsum_kernel<<<nb, 256, 0, stream>>>(counts, bsum, N);
    top_scan_kernel<<<1, 64, 0, stream>>>(bsum, boff, nb);
    local_scan_kernel<<<nb, 1024, 0, stream>>>(counts, boff, rowp, woff, N, E);
    scatter_kernel<<<(E + 255) / 256, 256, 0, stream>>>(src, dst, woff, srcs, E);
    agg1_csr_kernel<<<(N + 15) / 16, 256, 0, stream>>>(rowp, srcs, a_s1, a_d1, (const unsigned*)h1bf,
                                                       bias1, v2s, v2d, (unsigned*)hmid, a_s2, a_d2, N);
    agg2m_csr_kernel<<<(N + 15) / 16, 256, 0, stream>>>(rowp, srcs, a_s2, a_d2, (const unsigned*)hmid,
                                                        (unsigned*)Acat, N);
    zsd_mfma_kernel<<<(N + 63) / 64, 256, 0, stream>>>(Acat, wbigfrag, bz, zsd, N);
    edge_zsd_kernel<<<(E + 63) / 64, 256, 0, stream>>>(src, dst, (const unsigned*)zsd, fc3_w, fc3_b, out, E);
}

// Round 13
// 327.689 us; speedup vs baseline: 1.0384x; 1.0384x over previous
//
#include <hip/hip_runtime.h>
#include <hip/hip_bf16.h>
#include <math.h>

// N=50000, E=500000, SED=128, HID=64, H=2, F_node=128
// Round 13: R12 structure (layer-2 agg/GEMM swap) with fixes:
//  - prep: grid 256 + float4-vectorized Wbig compose (was 56us @ 1% occupancy)
//  - zsd/gemm1: explicit B-frag register batching per kt so loads pipeline
//    (R12 zsd VGPR=68 -> one b-frag in flight -> serialized; 52us @ 4% MfmaUtil)

typedef short short8 __attribute__((ext_vector_type(8)));
typedef float floatx4 __attribute__((ext_vector_type(4)));
typedef float v2f __attribute__((ext_vector_type(2)));
typedef unsigned uint2v __attribute__((ext_vector_type(2)));

__device__ __forceinline__ v2f bfpair(unsigned v) {
    uint2v t; t.x = v << 16; t.y = v & 0xFFFF0000u;
    return __builtin_bit_cast(v2f, t);
}
__device__ __forceinline__ unsigned short bfbits(float f) {
    return __builtin_bit_cast(unsigned short, __float2bfloat16(f));
}
__device__ __forceinline__ unsigned packbf(float a, float b) {
    return ((unsigned)bfbits(b) << 16) | (unsigned)bfbits(a);
}
__device__ __forceinline__ float lrelu(float v) { return v > 0.f ? v : 0.2f * v; }

// ---- prep: counts zero; c1; w1frag; Wbig frag (W2∘fc2); v2s/v2d; bz ----
__global__ void prep_kernel(const float* __restrict__ cls, const float* __restrict__ fc0_w,
                            const float* __restrict__ fc0_b, const float* __restrict__ W1,
                            const float* __restrict__ W2, const float* __restrict__ fc2_w,
                            const float* __restrict__ fc2_b, const float* __restrict__ bias2,
                            const float* __restrict__ att_s2, const float* __restrict__ att_d2,
                            float* __restrict__ c1,
                            __hip_bfloat16* __restrict__ w1frag,
                            __hip_bfloat16* __restrict__ wbigfrag,
                            float* __restrict__ v2s, float* __restrict__ v2d,
                            float* __restrict__ bz,
                            int* __restrict__ counts, int N) {
    int tid = threadIdx.x;
    int gstride = gridDim.x * blockDim.x;
    int g = blockIdx.x * blockDim.x + tid;
    for (int i = g; i < N; i += gstride) counts[i] = 0;
    if (blockIdx.x == 0) {
        __shared__ float s_sent[128];
        if (tid < 128) {
            float acc = fc0_b[tid];
            const float* row = fc0_w + (size_t)tid * 768;
            for (int k = 0; k < 768; ++k) acc += row[k] * cls[k];
            s_sent[tid] = acc;
        }
        __syncthreads();
        if (tid < 128) {
            float acc = 0.f;
            for (int k = 0; k < 128; ++k) acc += s_sent[k] * W1[(128 + k) * 128 + tid];
            c1[tid] = acc;
        }
    }
    // w1frag: B[k][n], k=kt*32+(l>>4)*8+j (KT=4), n=nt*16+(l&15) (NT=8)
    for (int i = g; i < 16384; i += gstride) {
        int j = i & 7, l = (i >> 3) & 63, nt = (i >> 9) & 7, kt = (i >> 12) & 3;
        int k = kt * 32 + (l >> 4) * 8 + j;
        int n = nt * 16 + (l & 15);
        w1frag[i] = __float2bfloat16(W1[k * 128 + n]);
    }
    // Wbig frag: K=256 (k=h*128+k'), NT=16 (n<128 zs, n>=128 zd)
    // Wbig[k][n] = 0.5 * sum_{c'} W2[k'][h*128+c'] * fc2row(n)[c']
    for (int i = g; i < 65536; i += gstride) {
        int j = i & 7, l = (i >> 3) & 63, nt = (i >> 9) & 15, kt = (i >> 13) & 7;
        int k = kt * 32 + (l >> 4) * 8 + j;
        int n = nt * 16 + (l & 15);
        int h = k >> 7, kp = k & 127;
        const float4* w2r4 = (const float4*)(W2 + (size_t)kp * 256 + h * 128);
        const float4* fcr4 = (const float4*)((n < 128) ? (fc2_w + (size_t)n * 256)
                                                       : (fc2_w + (size_t)(n - 128) * 256 + 128));
        float acc = 0.f;
        #pragma unroll 8
        for (int c4 = 0; c4 < 32; ++c4) {
            float4 a4 = w2r4[c4];
            float4 b4 = fcr4[c4];
            acc += a4.x * b4.x + a4.y * b4.y + a4.z * b4.z + a4.w * b4.w;
        }
        wbigfrag[i] = __float2bfloat16(0.5f * acc);
    }
    // v2s/v2d [h*128+k']: logits2 vectors  a_s2[n][h] = hmid[n] . v2s[h]
    for (int i = g; i < 256; i += gstride) {
        int h = i >> 7, kp = i & 127;
        const float* w2row = W2 + (size_t)kp * 256 + h * 128;
        const float* as = att_s2 + h * 128;
        const float* ad = att_d2 + h * 128;
        float s = 0.f, dd = 0.f;
        for (int c = 0; c < 128; ++c) { s += w2row[c] * as[c]; dd += w2row[c] * ad[c]; }
        v2s[i] = s; v2d[i] = dd;
    }
    // bz[256]: bias2 pushed through fc2 (+fc2_b on zd half)
    for (int i = g; i < 256; i += gstride) {
        const float* fcrow = (i < 128) ? (fc2_w + (size_t)i * 256)
                                       : (fc2_w + (size_t)(i - 128) * 256 + 128);
        float acc = 0.f;
        for (int c = 0; c < 128; ++c) acc += bias2[c] * fcrow[c];
        if (i >= 128) acc += fc2_b[i - 128];
        bz[i] = acc;
    }
}

// ---- CSR scan (hierarchical) ----
__global__ void __launch_bounds__(256) bsum_kernel(const int* __restrict__ counts,
                                                   int* __restrict__ bsum, int N) {
    int base = blockIdx.x * 1024;
    int tid = threadIdx.x;
    int v = 0;
    #pragma unroll
    for (int k = 0; k < 4; ++k) {
        int idx = base + k * 256 + tid;
        if (idx < N) v += counts[idx];
    }
    #pragma unroll
    for (int off = 1; off < 64; off <<= 1) v += __shfl_xor(v, off, 64);
    __shared__ int ws[4];
    if ((tid & 63) == 0) ws[tid >> 6] = v;
    __syncthreads();
    if (tid == 0) bsum[blockIdx.x] = ws[0] + ws[1] + ws[2] + ws[3];
}

__global__ void top_scan_kernel(const int* __restrict__ bsum, int* __restrict__ boff, int nb) {
    int lane = threadIdx.x;
    int v = (lane < nb) ? bsum[lane] : 0;
    int x = v;
    #pragma unroll
    for (int off = 1; off < 64; off <<= 1) {
        int t = __shfl_up(x, off, 64);
        if (lane >= off) x += t;
    }
    if (lane < nb) boff[lane] = x - v;
}

__global__ void __launch_bounds__(1024) local_scan_kernel(const int* __restrict__ counts,
                                                          const int* __restrict__ boff,
                                                          int* __restrict__ row, int* __restrict__ woff,
                                                          int N, int E) {
    int tid = threadIdx.x, lane = tid & 63, wv = tid >> 6;
    int base = blockIdx.x * 1024;
    __shared__ int wsum[16];
    int v = (base + tid < N) ? counts[base + tid] : 0;
    int x = v;
    #pragma unroll
    for (int off = 1; off < 64; off <<= 1) {
        int t = __shfl_up(x, off, 64);
        if (lane >= off) x += t;
    }
    if (lane == 63) wsum[wv] = x;
    __syncthreads();
    if (wv == 0 && lane < 16) {
        int y = wsum[lane];
        #pragma unroll
        for (int off = 1; off < 16; off <<= 1) {
            int t = __shfl_up(y, off, 64);
            if (lane >= off) y += t;
        }
        wsum[lane] = y;
    }
    __syncthreads();
    int excl = boff[blockIdx.x] + (wv ? wsum[wv - 1] : 0) + x - v;
    if (base + tid < N) { row[base + tid] = excl; woff[base + tid] = excl; }
    if (blockIdx.x == 0 && tid == 0) row[N] = E;
}

__global__ void scatter_kernel(const int* __restrict__ src, const int* __restrict__ dst,
                               int* __restrict__ woff, int* __restrict__ srcs, int E) {
    int e = blockIdx.x * blockDim.x + threadIdx.x;
    if (e < E) {
        int pos = atomicAdd(&woff[dst[e]], 1);
        srcs[pos] = src[e];
    }
}

// ---- gemm1 MFMA + fused degree count; B-frags batched into registers ----
__global__ void __launch_bounds__(256) gemm1_count_kernel(
        const float* __restrict__ x, const __hip_bfloat16* __restrict__ wfrag,
        const float* __restrict__ c1, const float* __restrict__ att_s, const float* __restrict__ att_d,
        __hip_bfloat16* __restrict__ h1bf, float* __restrict__ a_src, float* __restrict__ a_dst,
        const int* __restrict__ dst, int* __restrict__ counts, int E, int G1, int N) {
    if ((int)blockIdx.x >= G1) {
        int e = ((int)blockIdx.x - G1) * 256 + threadIdx.x;
        if (e < E) atomicAdd(&counts[dst[e]], 1);
        return;
    }
    int lane = threadIdx.x & 63, wv = threadIdx.x >> 6;
    int lo = lane & 15, quad = lane >> 4;
    int rowbase = ((int)blockIdx.x * 4 + wv) * 16;
    if (rowbase >= N) return;
    int arow = rowbase + lo; if (arow >= N) arow = N - 1;
    const float* ap = x + (size_t)arow * 128 + quad * 8;
    floatx4 acc[8];
    #pragma unroll
    for (int nt = 0; nt < 8; ++nt) acc[nt] = (floatx4){0.f, 0.f, 0.f, 0.f};
    const short8* bf = (const short8*)wfrag;
    #pragma unroll
    for (int kt = 0; kt < 4; ++kt) {
        float4 fa = *(const float4*)(ap + kt * 32);
        float4 fb = *(const float4*)(ap + kt * 32 + 4);
        short8 breg[8];
        #pragma unroll
        for (int nt = 0; nt < 8; ++nt) breg[nt] = bf[(kt * 8 + nt) * 64 + lane];
        short8 a;
        a[0] = (short)bfbits(fa.x); a[1] = (short)bfbits(fa.y);
        a[2] = (short)bfbits(fa.z); a[3] = (short)bfbits(fa.w);
        a[4] = (short)bfbits(fb.x); a[5] = (short)bfbits(fb.y);
        a[6] = (short)bfbits(fb.z); a[7] = (short)bfbits(fb.w);
        #pragma unroll
        for (int nt = 0; nt < 8; ++nt)
            acc[nt] = __builtin_amdgcn_mfma_f32_16x16x32_bf16(a, breg[nt], acc[nt], 0, 0, 0);
    }
    float ps0[4] = {0,0,0,0}, ps1[4] = {0,0,0,0}, pd0[4] = {0,0,0,0}, pd1[4] = {0,0,0,0};
    #pragma unroll
    for (int nt = 0; nt < 8; ++nt) {
        int ch = nt * 16 + lo;
        float cv = c1[ch], as_v = att_s[ch], ad_v = att_d[ch];
        #pragma unroll
        for (int r = 0; r < 4; ++r) {
            int row = rowbase + quad * 4 + r;
            float val = acc[nt][r] + cv;
            if (row < N) ((unsigned short*)h1bf)[(size_t)row * 128 + ch] = bfbits(val);
            if (nt < 4) { ps0[r] += val * as_v; pd0[r] += val * ad_v; }
            else        { ps1[r] += val * as_v; pd1[r] += val * ad_v; }
        }
    }
    #pragma unroll
    for (int r = 0; r < 4; ++r) {
        int row = rowbase + quad * 4 + r;
        float v0 = ps0[r], v1 = ps1[r], v2 = pd0[r], v3 = pd1[r];
        #pragma unroll
        for (int off = 1; off < 16; off <<= 1) {
            v0 += __shfl_xor(v0, off, 64); v1 += __shfl_xor(v1, off, 64);
            v2 += __shfl_xor(v2, off, 64); v3 += __shfl_xor(v3, off, 64);
        }
        if (lo == 0 && row < N) {
            a_src[row * 2 + 0] = v0; a_src[row * 2 + 1] = v1;
            a_dst[row * 2 + 0] = v2; a_dst[row * 2 + 1] = v3;
        }
    }
}

// ---- agg1: 16 lanes/dst; unroll-4; ELU -> hmid bf16; + fused logits2 ----
__global__ void __launch_bounds__(256) agg1_csr_kernel(
        const int* __restrict__ row, const int* __restrict__ srcs,
        const float* __restrict__ a_src, const float* __restrict__ a_dst,
        const unsigned* __restrict__ h1u, const float* __restrict__ bias1,
        const float* __restrict__ v2s, const float* __restrict__ v2d,
        unsigned* __restrict__ hmid_u, float* __restrict__ a_s2, float* __restrict__ a_d2, int N) {
    int tid = threadIdx.x;
    int d = blockIdx.x * 16 + (tid >> 4);
    if (d >= N) return;
    int q = tid & 15;
    int beg = row[d], end = row[d + 1];
    float2 adp = ((const float2*)a_dst)[d];
    float den0 = 0.f, den1 = 0.f;
    v2f facc2[4];
    #pragma unroll
    for (int m = 0; m < 4; ++m) facc2[m] = (v2f){0.f, 0.f};
    for (int i = beg; i < end; i += 4) {
        bool h1 = (i + 1) < end, h2 = (i + 2) < end, h3 = (i + 3) < end;
        int s0 = srcs[i];
        int s1 = h1 ? srcs[i + 1] : s0;
        int s2 = h2 ? srcs[i + 2] : s0;
        int s3 = h3 ? srcs[i + 3] : s0;
        float2 as0 = ((const float2*)a_src)[s0];
        float2 as1 = ((const float2*)a_src)[s1];
        float2 as2 = ((const float2*)a_src)[s2];
        float2 as3 = ((const float2*)a_src)[s3];
        uint4 u0 = ((const uint4*)(h1u + (size_t)s0 * 64))[q];
        uint4 u1 = ((const uint4*)(h1u + (size_t)s1 * 64))[q];
        uint4 u2 = ((const uint4*)(h1u + (size_t)s2 * 64))[q];
        uint4 u3 = ((const uint4*)(h1u + (size_t)s3 * 64))[q];
        float e00 = __expf(lrelu(as0.x + adp.x));
        float e01 = __expf(lrelu(as0.y + adp.y));
        float e10 = h1 ? __expf(lrelu(as1.x + adp.x)) : 0.f;
        float e11 = h1 ? __expf(lrelu(as1.y + adp.y)) : 0.f;
        float e20 = h2 ? __expf(lrelu(as2.x + adp.x)) : 0.f;
        float e21 = h2 ? __expf(lrelu(as2.y + adp.y)) : 0.f;
        float e30 = h3 ? __expf(lrelu(as3.x + adp.x)) : 0.f;
        float e31 = h3 ? __expf(lrelu(as3.y + adp.y)) : 0.f;
        den0 += e00 + e10 + e20 + e30;
        den1 += e01 + e11 + e21 + e31;
        float w0 = (q < 8) ? e00 : e01;
        float w1 = (q < 8) ? e10 : e11;
        float w2 = (q < 8) ? e20 : e21;
        float w3 = (q < 8) ? e30 : e31;
        facc2[0] += bfpair(u0.x) * w0 + bfpair(u1.x) * w1 + bfpair(u2.x) * w2 + bfpair(u3.x) * w3;
        facc2[1] += bfpair(u0.y) * w0 + bfpair(u1.y) * w1 + bfpair(u2.y) * w2 + bfpair(u3.y) * w3;
        facc2[2] += bfpair(u0.z) * w0 + bfpair(u1.z) * w1 + bfpair(u2.z) * w2 + bfpair(u3.z) * w3;
        facc2[3] += bfpair(u0.w) * w0 + bfpair(u1.w) * w1 + bfpair(u2.w) * w2 + bfpair(u3.w) * w3;
    }
    float inv = 1.f / (((q < 8) ? den0 : den1) + 1e-16f);
    int c0 = 8 * q;
    float v[8];
    #pragma unroll
    for (int m = 0; m < 4; ++m) {
        float va = facc2[m].x * inv + bias1[c0 + 2 * m];
        float vb = facc2[m].y * inv + bias1[c0 + 2 * m + 1];
        v[2 * m]     = va > 0.f ? va : expm1f(va);
        v[2 * m + 1] = vb > 0.f ? vb : expm1f(vb);
    }
    uint4 o;
    o.x = packbf(v[0], v[1]); o.y = packbf(v[2], v[3]);
    o.z = packbf(v[4], v[5]); o.w = packbf(v[6], v[7]);
    ((uint4*)(hmid_u + (size_t)d * 64))[q] = o;
    // fused logits2: a_s2[d][h] = hmid[d] . v2s[h] ; reduce over 16-lane group
    float s20 = 0.f, s21 = 0.f, d20 = 0.f, d21 = 0.f;
    #pragma unroll
    for (int m = 0; m < 8; ++m) {
        float hv = v[m];
        s20 += hv * v2s[c0 + m];
        s21 += hv * v2s[128 + c0 + m];
        d20 += hv * v2d[c0 + m];
        d21 += hv * v2d[128 + c0 + m];
    }
    #pragma unroll
    for (int off = 1; off < 16; off <<= 1) {
        s20 += __shfl_xor(s20, off, 64); s21 += __shfl_xor(s21, off, 64);
        d20 += __shfl_xor(d20, off, 64); d21 += __shfl_xor(d21, off, 64);
    }
    if (q == 0) {
        ((float2*)a_s2)[d] = make_float2(s20, s21);
        ((float2*)a_d2)[d] = make_float2(d20, d21);
    }
}

// ---- agg2m: 16 lanes/dst; gather hmid (256B); dual-head accumulate -> Acat ----
__global__ void __launch_bounds__(256) agg2m_csr_kernel(
        const int* __restrict__ row, const int* __restrict__ srcs,
        const float* __restrict__ a_src, const float* __restrict__ a_dst,
        const unsigned* __restrict__ hmid_u, unsigned* __restrict__ Acat_u, int N) {
    int tid = threadIdx.x;
    int d = blockIdx.x * 16 + (tid >> 4);
    if (d >= N) return;
    int q = tid & 15;
    int beg = row[d], end = row[d + 1];
    float2 adp = ((const float2*)a_dst)[d];
    float den0 = 0.f, den1 = 0.f;
    v2f a0[4], a1[4];
    #pragma unroll
    for (int m = 0; m < 4; ++m) { a0[m] = (v2f){0.f, 0.f}; a1[m] = (v2f){0.f, 0.f}; }
    for (int i = beg; i < end; i += 4) {
        bool h1 = (i + 1) < end, h2 = (i + 2) < end, h3 = (i + 3) < end;
        int s0 = srcs[i];
        int s1 = h1 ? srcs[i + 1] : s0;
        int s2 = h2 ? srcs[i + 2] : s0;
        int s3 = h3 ? srcs[i + 3] : s0;
        float2 as0 = ((const float2*)a_src)[s0];
        float2 as1 = ((const float2*)a_src)[s1];
        float2 as2 = ((const float2*)a_src)[s2];
        float2 as3 = ((const float2*)a_src)[s3];
        uint4 u0 = ((const uint4*)(hmid_u + (size_t)s0 * 64))[q];
        uint4 u1 = ((const uint4*)(hmid_u + (size_t)s1 * 64))[q];
        uint4 u2 = ((const uint4*)(hmid_u + (size_t)s2 * 64))[q];
        uint4 u3 = ((const uint4*)(hmid_u + (size_t)s3 * 64))[q];
        float e00 = __expf(lrelu(as0.x + adp.x));
        float e01 = __expf(lrelu(as0.y + adp.y));
        float e10 = h1 ? __expf(lrelu(as1.x + adp.x)) : 0.f;
        float e11 = h1 ? __expf(lrelu(as1.y + adp.y)) : 0.f;
        float e20 = h2 ? __expf(lrelu(as2.x + adp.x)) : 0.f;
        float e21 = h2 ? __expf(lrelu(as2.y + adp.y)) : 0.f;
        float e30 = h3 ? __expf(lrelu(as3.x + adp.x)) : 0.f;
        float e31 = h3 ? __expf(lrelu(as3.y + adp.y)) : 0.f;
        den0 += e00 + e10 + e20 + e30;
        den1 += e01 + e11 + e21 + e31;
        v2f p0x = bfpair(u0.x), p0y = bfpair(u0.y), p0z = bfpair(u0.z), p0w = bfpair(u0.w);
        v2f p1x = bfpair(u1.x), p1y = bfpair(u1.y), p1z = bfpair(u1.z), p1w = bfpair(u1.w);
        v2f p2x = bfpair(u2.x), p2y = bfpair(u2.y), p2z = bfpair(u2.z), p2w = bfpair(u2.w);
        v2f p3x = bfpair(u3.x), p3y = bfpair(u3.y), p3z = bfpair(u3.z), p3w = bfpair(u3.w);
        a0[0] += p0x * e00 + p1x * e10 + p2x * e20 + p3x * e30;
        a0[1] += p0y * e00 + p1y * e10 + p2y * e20 + p3y * e30;
        a0[2] += p0z * e00 + p1z * e10 + p2z * e20 + p3z * e30;
        a0[3] += p0w * e00 + p1w * e10 + p2w * e20 + p3w * e30;
        a1[0] += p0x * e01 + p1x * e11 + p2x * e21 + p3x * e31;
        a1[1] += p0y * e01 + p1y * e11 + p2y * e21 + p3y * e31;
        a1[2] += p0z * e01 + p1z * e11 + p2z * e21 + p3z * e31;
        a1[3] += p0w * e01 + p1w * e11 + p2w * e21 + p3w * e31;
    }
    float inv0 = 1.f / (den0 + 1e-16f);
    float inv1 = 1.f / (den1 + 1e-16f);
    uint4 o0, o1;
    o0.x = packbf(a0[0].x * inv0, a0[0].y * inv0);
    o0.y = packbf(a0[1].x * inv0, a0[1].y * inv0);
    o0.z = packbf(a0[2].x * inv0, a0[2].y * inv0);
    o0.w = packbf(a0[3].x * inv0, a0[3].y * inv0);
    o1.x = packbf(a1[0].x * inv1, a1[0].y * inv1);
    o1.y = packbf(a1[1].x * inv1, a1[1].y * inv1);
    o1.z = packbf(a1[2].x * inv1, a1[2].y * inv1);
    o1.w = packbf(a1[3].x * inv1, a1[3].y * inv1);
    uint4* orow = (uint4*)(Acat_u + (size_t)d * 128);
    orow[q] = o0;        // head-0 half
    orow[16 + q] = o1;   // head-1 half
}

// ---- zsd MFMA: zsd[N,256](bf16) = Acat[N,256] @ Wbigfrag + bz; batched B ----
__global__ void __launch_bounds__(256) zsd_mfma_kernel(
        const __hip_bfloat16* __restrict__ Acat, const __hip_bfloat16* __restrict__ wfrag,
        const float* __restrict__ bz, __hip_bfloat16* __restrict__ zsd, int N) {
    int lane = threadIdx.x & 63, wv = threadIdx.x >> 6;
    int lo = lane & 15, quad = lane >> 4;
    int rowbase = (blockIdx.x * 4 + wv) * 16;
    if (rowbase >= N) return;
    int arow = rowbase + lo; if (arow >= N) arow = N - 1;
    const __hip_bfloat16* ap = Acat + (size_t)arow * 256 + quad * 8;
    floatx4 acc[16];
    #pragma unroll
    for (int nt = 0; nt < 16; ++nt) acc[nt] = (floatx4){0.f, 0.f, 0.f, 0.f};
    const short8* bf = (const short8*)wfrag;
    #pragma unroll
    for (int kt = 0; kt < 8; ++kt) {
        short8 a = *(const short8*)(ap + kt * 32);
        short8 breg[16];
        #pragma unroll
        for (int nt = 0; nt < 16; ++nt) breg[nt] = bf[(kt * 16 + nt) * 64 + lane];
        #pragma unroll
        for (int nt = 0; nt < 16; ++nt)
            acc[nt] = __builtin_amdgcn_mfma_f32_16x16x32_bf16(a, breg[nt], acc[nt], 0, 0, 0);
    }
    #pragma unroll
    for (int nt = 0; nt < 16; ++nt) {
        int ch = nt * 16 + lo;
        float bv = bz[ch];
        #pragma unroll
        for (int r = 0; r < 4; ++r) {
            int row = rowbase + quad * 4 + r;
            if (row < N) ((unsigned short*)zsd)[(size_t)row * 256 + ch] = bfbits(acc[nt][r] + bv);
        }
    }
}

// ---- edge head: batched gathers (8 rounds), channel-split, shfl_xor(16) add ----
__global__ void __launch_bounds__(256) edge_zsd_kernel(
        const int* __restrict__ src, const int* __restrict__ dst,
        const unsigned* __restrict__ zsd_u, const float* __restrict__ fc3_w,
        const float* __restrict__ fc3_b, float* __restrict__ out, int E) {
    int lane = threadIdx.x & 63, wv = threadIdx.x >> 6;
    int g = lane >> 5, r = (lane >> 4) & 1, q = lane & 15;
    int base = (blockIdx.x * 4 + wv) * 16;
    if (base >= E) return;
    v2f f30 = {fc3_w[8 * q + 4 * r + 0], fc3_w[8 * q + 4 * r + 1]};
    v2f f31 = {fc3_w[8 * q + 4 * r + 2], fc3_w[8 * q + 4 * r + 3]};
    float b3 = fc3_b[0];
    int nodes[8];
    #pragma unroll
    for (int j = 0; j < 8; ++j) {
        int e = base + 2 * j + g;
        int ec = e < E ? e : E - 1;
        nodes[j] = r ? dst[ec] : src[ec];
    }
    uint4 rows[8];
    #pragma unroll
    for (int j = 0; j < 8; ++j)
        rows[j] = ((const uint4*)(zsd_u + (size_t)nodes[j] * 128 + (r << 6)))[q];
    #pragma unroll
    for (int j = 0; j < 8; ++j) {
        uint4 mine = rows[j];
        unsigned sx = (unsigned)__shfl_xor((int)mine.x, 16, 64);
        unsigned sy = (unsigned)__shfl_xor((int)mine.y, 16, 64);
        unsigned sz = (unsigned)__shfl_xor((int)mine.z, 16, 64);
        unsigned sw = (unsigned)__shfl_xor((int)mine.w, 16, 64);
        unsigned mA = r ? mine.z : mine.x;
        unsigned mB = r ? mine.w : mine.y;
        unsigned oA = r ? sz : sx;
        unsigned oB = r ? sw : sy;
        v2f sA = bfpair(mA) + bfpair(oA);
        v2f sB = bfpair(mB) + bfpair(oB);
        sA.x = fmaxf(sA.x, 0.f); sA.y = fmaxf(sA.y, 0.f);
        sB.x = fmaxf(sB.x, 0.f); sB.y = fmaxf(sB.y, 0.f);
        v2f p2 = sA * f30 + sB * f31;
        float p = p2.x + p2.y;
        #pragma unroll
        for (int off = 1; off < 32; off <<= 1) p += __shfl_xor(p, off, 64);
        int e = base + 2 * j + g;
        if ((lane & 31) == 0 && e < E)
            out[e] = 1.f / (1.f + expf(-(p + b3)));
    }
}

extern "C" void kernel_launch(void* const* d_in, const int* in_sizes, int n_in,
                              void* d_out, int out_size, void* d_ws, size_t ws_size,
                              hipStream_t stream) {
    const float* x      = (const float*)d_in[0];
    const int*   ei     = (const int*)d_in[1];
    const float* cls    = (const float*)d_in[2];
    const float* fc0_w  = (const float*)d_in[3];
    const float* fc0_b  = (const float*)d_in[4];
    const float* W1     = (const float*)d_in[5];
    const float* att_s1 = (const float*)d_in[6];
    const float* att_d1 = (const float*)d_in[7];
    const float* bias1  = (const float*)d_in[8];
    const float* W2     = (const float*)d_in[9];
    const float* att_s2 = (const float*)d_in[10];
    const float* att_d2 = (const float*)d_in[11];
    const float* bias2  = (const float*)d_in[12];
    const float* fc2_w  = (const float*)d_in[13];
    const float* fc2_b  = (const float*)d_in[14];
    const float* fc3_w  = (const float*)d_in[15];
    const float* fc3_b  = (const float*)d_in[16];
    float* out = (float*)d_out;

    int N = in_sizes[0] / 128;
    int E = in_sizes[1] / 2;
    const int* src = ei;
    const int* dst = ei + E;
    int nb = (N + 1023) / 1024;

    float* w = (float*)d_ws;
    size_t off = 0;
    auto alloc = [&](size_t n) { float* p = w + off; off += (n + 63) & ~(size_t)63; return p; };
    float* c1       = alloc(128);
    float* w1fragf  = alloc(16384 / 2);
    float* wbigf    = alloc(65536 / 2);
    float* v2s      = alloc(256);
    float* v2d      = alloc(256);
    float* bz       = alloc(256);
    float* a_s1     = alloc((size_t)N * 2);
    float* a_d1     = alloc((size_t)N * 2);
    float* a_s2     = alloc((size_t)N * 2);
    float* a_d2     = alloc((size_t)N * 2);
    float* h1bff    = alloc((size_t)N * 64);   // N*128 bf16
    float* hmidf    = alloc((size_t)N * 64);   // N*128 bf16
    float* Acatf    = alloc((size_t)N * 128);  // N*256 bf16
    float* zsdf     = alloc((size_t)N * 128);  // N*256 bf16
    int* counts = (int*)alloc(N);
    int* rowp   = (int*)alloc(N + 1);
    int* woff   = (int*)alloc(N);
    int* srcs   = (int*)alloc(E);
    int* bsum   = (int*)alloc(64);
    int* boff   = (int*)alloc(64);
    __hip_bfloat16* w1frag   = (__hip_bfloat16*)w1fragf;
    __hip_bfloat16* wbigfrag = (__hip_bfloat16*)wbigf;
    __hip_bfloat16* h1bf     = (__hip_bfloat16*)h1bff;
    __hip_bfloat16* hmid     = (__hip_bfloat16*)hmidf;
    __hip_bfloat16* Acat     = (__hip_bfloat16*)Acatf;
    __hip_bfloat16* zsd      = (__hip_bfloat16*)zsdf;

    prep_kernel<<<256, 256, 0, stream>>>(cls, fc0_w, fc0_b, W1, W2, fc2_w, fc2_b, bias2,
                                         att_s2, att_d2, c1, w1frag, wbigfrag, v2s, v2d, bz,
                                         counts, N);
    int G1 = (N + 63) / 64;
    int G2 = (E + 255) / 256;
    gemm1_count_kernel<<<G1 + G2, 256, 0, stream>>>(x, w1frag, c1, att_s1, att_d1, h1bf, a_s1, a_d1,
                                                    dst, counts, E, G1, N);
    bsum_kernel<<<nb, 256, 0, stream>>>(counts, bsum, N);
    top_scan_kernel<<<1, 64, 0, stream>>>(bsum, boff, nb);
    local_scan_kernel<<<nb, 1024, 0, stream>>>(counts, boff, rowp, woff, N, E);
    scatter_kernel<<<(E + 255) / 256, 256, 0, stream>>>(src, dst, woff, srcs, E);
    agg1_csr_kernel<<<(N + 15) / 16, 256, 0, stream>>>(rowp, srcs, a_s1, a_d1, (const unsigned*)h1bf,
                                                       bias1, v2s, v2d, (unsigned*)hmid, a_s2, a_d2, N);
    agg2m_csr_kernel<<<(N + 15) / 16, 256, 0, stream>>>(rowp, srcs, a_s2, a_d2, (const unsigned*)hmid,
                                                        (unsigned*)Acat, N);
    zsd_mfma_kernel<<<(N + 63) / 64, 256, 0, stream>>>(Acat, wbigfrag, bz, zsd, N);
    edge_zsd_kernel<<<(E + 63) / 64, 256, 0, stream>>>(src, dst, (const unsigned*)zsd, fc3_w, fc3_b, out, E);
}

// Round 14
// 327.687 us; speedup vs baseline: 1.0384x; 1.0000x over previous
//
#include <hip/hip_runtime.h>
#include <hip/hip_bf16.h>
#include <math.h>

// N=50000, E=500000, SED=128, HID=64, H=2, F_node=128
// Round 14: R13 + zsd B-matrix staged through LDS (Wbig frag = 128 KB thrashes
// the 32 KB L1 -> every B-load was an ~200cyc L2 round trip, serialized;
// gemm1's 32KB table fits L1 which is why it was fine). 4 stages x 32 KB.

typedef short short8 __attribute__((ext_vector_type(8)));
typedef float floatx4 __attribute__((ext_vector_type(4)));
typedef float v2f __attribute__((ext_vector_type(2)));
typedef unsigned uint2v __attribute__((ext_vector_type(2)));

__device__ __forceinline__ v2f bfpair(unsigned v) {
    uint2v t; t.x = v << 16; t.y = v & 0xFFFF0000u;
    return __builtin_bit_cast(v2f, t);
}
__device__ __forceinline__ unsigned short bfbits(float f) {
    return __builtin_bit_cast(unsigned short, __float2bfloat16(f));
}
__device__ __forceinline__ unsigned packbf(float a, float b) {
    return ((unsigned)bfbits(b) << 16) | (unsigned)bfbits(a);
}
__device__ __forceinline__ float lrelu(float v) { return v > 0.f ? v : 0.2f * v; }

// ---- prep: counts zero; c1; w1frag; Wbig frag (W2∘fc2); v2s/v2d; bz ----
__global__ void prep_kernel(const float* __restrict__ cls, const float* __restrict__ fc0_w,
                            const float* __restrict__ fc0_b, const float* __restrict__ W1,
                            const float* __restrict__ W2, const float* __restrict__ fc2_w,
                            const float* __restrict__ fc2_b, const float* __restrict__ bias2,
                            const float* __restrict__ att_s2, const float* __restrict__ att_d2,
                            float* __restrict__ c1,
                            __hip_bfloat16* __restrict__ w1frag,
                            __hip_bfloat16* __restrict__ wbigfrag,
                            float* __restrict__ v2s, float* __restrict__ v2d,
                            float* __restrict__ bz,
                            int* __restrict__ counts, int N) {
    int tid = threadIdx.x;
    int gstride = gridDim.x * blockDim.x;
    int g = blockIdx.x * blockDim.x + tid;
    for (int i = g; i < N; i += gstride) counts[i] = 0;
    if (blockIdx.x == 0) {
        __shared__ float s_sent[128];
        if (tid < 128) {
            float acc = fc0_b[tid];
            const float* row = fc0_w + (size_t)tid * 768;
            for (int k = 0; k < 768; ++k) acc += row[k] * cls[k];
            s_sent[tid] = acc;
        }
        __syncthreads();
        if (tid < 128) {
            float acc = 0.f;
            for (int k = 0; k < 128; ++k) acc += s_sent[k] * W1[(128 + k) * 128 + tid];
            c1[tid] = acc;
        }
    }
    for (int i = g; i < 16384; i += gstride) {
        int j = i & 7, l = (i >> 3) & 63, nt = (i >> 9) & 7, kt = (i >> 12) & 3;
        int k = kt * 32 + (l >> 4) * 8 + j;
        int n = nt * 16 + (l & 15);
        w1frag[i] = __float2bfloat16(W1[k * 128 + n]);
    }
    // Wbig frag: K=256 (k=h*128+k'), NT=16; Wbig[k][n]=0.5*sum W2[k'][h*128+c']*fc2row(n)[c']
    for (int i = g; i < 65536; i += gstride) {
        int j = i & 7, l = (i >> 3) & 63, nt = (i >> 9) & 15, kt = (i >> 13) & 7;
        int k = kt * 32 + (l >> 4) * 8 + j;
        int n = nt * 16 + (l & 15);
        int h = k >> 7, kp = k & 127;
        const float4* w2r4 = (const float4*)(W2 + (size_t)kp * 256 + h * 128);
        const float4* fcr4 = (const float4*)((n < 128) ? (fc2_w + (size_t)n * 256)
                                                       : (fc2_w + (size_t)(n - 128) * 256 + 128));
        float acc = 0.f;
        #pragma unroll 8
        for (int c4 = 0; c4 < 32; ++c4) {
            float4 a4 = w2r4[c4];
            float4 b4 = fcr4[c4];
            acc += a4.x * b4.x + a4.y * b4.y + a4.z * b4.z + a4.w * b4.w;
        }
        wbigfrag[i] = __float2bfloat16(0.5f * acc);
    }
    for (int i = g; i < 256; i += gstride) {
        int h = i >> 7, kp = i & 127;
        const float* w2row = W2 + (size_t)kp * 256 + h * 128;
        const float* as = att_s2 + h * 128;
        const float* ad = att_d2 + h * 128;
        float s = 0.f, dd = 0.f;
        for (int c = 0; c < 128; ++c) { s += w2row[c] * as[c]; dd += w2row[c] * ad[c]; }
        v2s[i] = s; v2d[i] = dd;
    }
    for (int i = g; i < 256; i += gstride) {
        const float* fcrow = (i < 128) ? (fc2_w + (size_t)i * 256)
                                       : (fc2_w + (size_t)(i - 128) * 256 + 128);
        float acc = 0.f;
        for (int c = 0; c < 128; ++c) acc += bias2[c] * fcrow[c];
        if (i >= 128) acc += fc2_b[i - 128];
        bz[i] = acc;
    }
}

// ---- CSR scan (hierarchical) ----
__global__ void __launch_bounds__(256) bsum_kernel(const int* __restrict__ counts,
                                                   int* __restrict__ bsum, int N) {
    int base = blockIdx.x * 1024;
    int tid = threadIdx.x;
    int v = 0;
    #pragma unroll
    for (int k = 0; k < 4; ++k) {
        int idx = base + k * 256 + tid;
        if (idx < N) v += counts[idx];
    }
    #pragma unroll
    for (int off = 1; off < 64; off <<= 1) v += __shfl_xor(v, off, 64);
    __shared__ int ws[4];
    if ((tid & 63) == 0) ws[tid >> 6] = v;
    __syncthreads();
    if (tid == 0) bsum[blockIdx.x] = ws[0] + ws[1] + ws[2] + ws[3];
}

__global__ void top_scan_kernel(const int* __restrict__ bsum, int* __restrict__ boff, int nb) {
    int lane = threadIdx.x;
    int v = (lane < nb) ? bsum[lane] : 0;
    int x = v;
    #pragma unroll
    for (int off = 1; off < 64; off <<= 1) {
        int t = __shfl_up(x, off, 64);
        if (lane >= off) x += t;
    }
    if (lane < nb) boff[lane] = x - v;
}

__global__ void __launch_bounds__(1024) local_scan_kernel(const int* __restrict__ counts,
                                                          const int* __restrict__ boff,
                                                          int* __restrict__ row, int* __restrict__ woff,
                                                          int N, int E) {
    int tid = threadIdx.x, lane = tid & 63, wv = tid >> 6;
    int base = blockIdx.x * 1024;
    __shared__ int wsum[16];
    int v = (base + tid < N) ? counts[base + tid] : 0;
    int x = v;
    #pragma unroll
    for (int off = 1; off < 64; off <<= 1) {
        int t = __shfl_up(x, off, 64);
        if (lane >= off) x += t;
    }
    if (lane == 63) wsum[wv] = x;
    __syncthreads();
    if (wv == 0 && lane < 16) {
        int y = wsum[lane];
        #pragma unroll
        for (int off = 1; off < 16; off <<= 1) {
            int t = __shfl_up(y, off, 64);
            if (lane >= off) y += t;
        }
        wsum[lane] = y;
    }
    __syncthreads();
    int excl = boff[blockIdx.x] + (wv ? wsum[wv - 1] : 0) + x - v;
    if (base + tid < N) { row[base + tid] = excl; woff[base + tid] = excl; }
    if (blockIdx.x == 0 && tid == 0) row[N] = E;
}

__global__ void scatter_kernel(const int* __restrict__ src, const int* __restrict__ dst,
                               int* __restrict__ woff, int* __restrict__ srcs, int E) {
    int e = blockIdx.x * blockDim.x + threadIdx.x;
    if (e < E) {
        int pos = atomicAdd(&woff[dst[e]], 1);
        srcs[pos] = src[e];
    }
}

// ---- gemm1 MFMA + fused degree count ----
__global__ void __launch_bounds__(256) gemm1_count_kernel(
        const float* __restrict__ x, const __hip_bfloat16* __restrict__ wfrag,
        const float* __restrict__ c1, const float* __restrict__ att_s, const float* __restrict__ att_d,
        __hip_bfloat16* __restrict__ h1bf, float* __restrict__ a_src, float* __restrict__ a_dst,
        const int* __restrict__ dst, int* __restrict__ counts, int E, int G1, int N) {
    if ((int)blockIdx.x >= G1) {
        int e = ((int)blockIdx.x - G1) * 256 + threadIdx.x;
        if (e < E) atomicAdd(&counts[dst[e]], 1);
        return;
    }
    int lane = threadIdx.x & 63, wv = threadIdx.x >> 6;
    int lo = lane & 15, quad = lane >> 4;
    int rowbase = ((int)blockIdx.x * 4 + wv) * 16;
    if (rowbase >= N) return;
    int arow = rowbase + lo; if (arow >= N) arow = N - 1;
    const float* ap = x + (size_t)arow * 128 + quad * 8;
    floatx4 acc[8];
    #pragma unroll
    for (int nt = 0; nt < 8; ++nt) acc[nt] = (floatx4){0.f, 0.f, 0.f, 0.f};
    const short8* bf = (const short8*)wfrag;
    #pragma unroll
    for (int kt = 0; kt < 4; ++kt) {
        float4 fa = *(const float4*)(ap + kt * 32);
        float4 fb = *(const float4*)(ap + kt * 32 + 4);
        short8 a;
        a[0] = (short)bfbits(fa.x); a[1] = (short)bfbits(fa.y);
        a[2] = (short)bfbits(fa.z); a[3] = (short)bfbits(fa.w);
        a[4] = (short)bfbits(fb.x); a[5] = (short)bfbits(fb.y);
        a[6] = (short)bfbits(fb.z); a[7] = (short)bfbits(fb.w);
        #pragma unroll
        for (int nt = 0; nt < 8; ++nt)
            acc[nt] = __builtin_amdgcn_mfma_f32_16x16x32_bf16(a, bf[(kt * 8 + nt) * 64 + lane], acc[nt], 0, 0, 0);
    }
    float ps0[4] = {0,0,0,0}, ps1[4] = {0,0,0,0}, pd0[4] = {0,0,0,0}, pd1[4] = {0,0,0,0};
    #pragma unroll
    for (int nt = 0; nt < 8; ++nt) {
        int ch = nt * 16 + lo;
        float cv = c1[ch], as_v = att_s[ch], ad_v = att_d[ch];
        #pragma unroll
        for (int r = 0; r < 4; ++r) {
            int row = rowbase + quad * 4 + r;
            float val = acc[nt][r] + cv;
            if (row < N) ((unsigned short*)h1bf)[(size_t)row * 128 + ch] = bfbits(val);
            if (nt < 4) { ps0[r] += val * as_v; pd0[r] += val * ad_v; }
            else        { ps1[r] += val * as_v; pd1[r] += val * ad_v; }
        }
    }
    #pragma unroll
    for (int r = 0; r < 4; ++r) {
        int row = rowbase + quad * 4 + r;
        float v0 = ps0[r], v1 = ps1[r], v2 = pd0[r], v3 = pd1[r];
        #pragma unroll
        for (int off = 1; off < 16; off <<= 1) {
            v0 += __shfl_xor(v0, off, 64); v1 += __shfl_xor(v1, off, 64);
            v2 += __shfl_xor(v2, off, 64); v3 += __shfl_xor(v3, off, 64);
        }
        if (lo == 0 && row < N) {
            a_src[row * 2 + 0] = v0; a_src[row * 2 + 1] = v1;
            a_dst[row * 2 + 0] = v2; a_dst[row * 2 + 1] = v3;
        }
    }
}

// ---- agg1: 16 lanes/dst; unroll-4; ELU -> hmid bf16; + fused logits2 ----
__global__ void __launch_bounds__(256) agg1_csr_kernel(
        const int* __restrict__ row, const int* __restrict__ srcs,
        const float* __restrict__ a_src, const float* __restrict__ a_dst,
        const unsigned* __restrict__ h1u, const float* __restrict__ bias1,
        const float* __restrict__ v2s, const float* __restrict__ v2d,
        unsigned* __restrict__ hmid_u, float* __restrict__ a_s2, float* __restrict__ a_d2, int N) {
    int tid = threadIdx.x;
    int d = blockIdx.x * 16 + (tid >> 4);
    if (d >= N) return;
    int q = tid & 15;
    int beg = row[d], end = row[d + 1];
    float2 adp = ((const float2*)a_dst)[d];
    float den0 = 0.f, den1 = 0.f;
    v2f facc2[4];
    #pragma unroll
    for (int m = 0; m < 4; ++m) facc2[m] = (v2f){0.f, 0.f};
    for (int i = beg; i < end; i += 4) {
        bool h1 = (i + 1) < end, h2 = (i + 2) < end, h3 = (i + 3) < end;
        int s0 = srcs[i];
        int s1 = h1 ? srcs[i + 1] : s0;
        int s2 = h2 ? srcs[i + 2] : s0;
        int s3 = h3 ? srcs[i + 3] : s0;
        float2 as0 = ((const float2*)a_src)[s0];
        float2 as1 = ((const float2*)a_src)[s1];
        float2 as2 = ((const float2*)a_src)[s2];
        float2 as3 = ((const float2*)a_src)[s3];
        uint4 u0 = ((const uint4*)(h1u + (size_t)s0 * 64))[q];
        uint4 u1 = ((const uint4*)(h1u + (size_t)s1 * 64))[q];
        uint4 u2 = ((const uint4*)(h1u + (size_t)s2 * 64))[q];
        uint4 u3 = ((const uint4*)(h1u + (size_t)s3 * 64))[q];
        float e00 = __expf(lrelu(as0.x + adp.x));
        float e01 = __expf(lrelu(as0.y + adp.y));
        float e10 = h1 ? __expf(lrelu(as1.x + adp.x)) : 0.f;
        float e11 = h1 ? __expf(lrelu(as1.y + adp.y)) : 0.f;
        float e20 = h2 ? __expf(lrelu(as2.x + adp.x)) : 0.f;
        float e21 = h2 ? __expf(lrelu(as2.y + adp.y)) : 0.f;
        float e30 = h3 ? __expf(lrelu(as3.x + adp.x)) : 0.f;
        float e31 = h3 ? __expf(lrelu(as3.y + adp.y)) : 0.f;
        den0 += e00 + e10 + e20 + e30;
        den1 += e01 + e11 + e21 + e31;
        float w0 = (q < 8) ? e00 : e01;
        float w1 = (q < 8) ? e10 : e11;
        float w2 = (q < 8) ? e20 : e21;
        float w3 = (q < 8) ? e30 : e31;
        facc2[0] += bfpair(u0.x) * w0 + bfpair(u1.x) * w1 + bfpair(u2.x) * w2 + bfpair(u3.x) * w3;
        facc2[1] += bfpair(u0.y) * w0 + bfpair(u1.y) * w1 + bfpair(u2.y) * w2 + bfpair(u3.y) * w3;
        facc2[2] += bfpair(u0.z) * w0 + bfpair(u1.z) * w1 + bfpair(u2.z) * w2 + bfpair(u3.z) * w3;
        facc2[3] += bfpair(u0.w) * w0 + bfpair(u1.w) * w1 + bfpair(u2.w) * w2 + bfpair(u3.w) * w3;
    }
    float inv = 1.f / (((q < 8) ? den0 : den1) + 1e-16f);
    int c0 = 8 * q;
    float v[8];
    #pragma unroll
    for (int m = 0; m < 4; ++m) {
        float va = facc2[m].x * inv + bias1[c0 + 2 * m];
        float vb = facc2[m].y * inv + bias1[c0 + 2 * m + 1];
        v[2 * m]     = va > 0.f ? va : expm1f(va);
        v[2 * m + 1] = vb > 0.f ? vb : expm1f(vb);
    }
    uint4 o;
    o.x = packbf(v[0], v[1]); o.y = packbf(v[2], v[3]);
    o.z = packbf(v[4], v[5]); o.w = packbf(v[6], v[7]);
    ((uint4*)(hmid_u + (size_t)d * 64))[q] = o;
    float s20 = 0.f, s21 = 0.f, d20 = 0.f, d21 = 0.f;
    #pragma unroll
    for (int m = 0; m < 8; ++m) {
        float hv = v[m];
        s20 += hv * v2s[c0 + m];
        s21 += hv * v2s[128 + c0 + m];
        d20 += hv * v2d[c0 + m];
        d21 += hv * v2d[128 + c0 + m];
    }
    #pragma unroll
    for (int off = 1; off < 16; off <<= 1) {
        s20 += __shfl_xor(s20, off, 64); s21 += __shfl_xor(s21, off, 64);
        d20 += __shfl_xor(d20, off, 64); d21 += __shfl_xor(d21, off, 64);
    }
    if (q == 0) {
        ((float2*)a_s2)[d] = make_float2(s20, s21);
        ((float2*)a_d2)[d] = make_float2(d20, d21);
    }
}

// ---- agg2m: 16 lanes/dst; gather hmid (256B); dual-head accumulate -> Acat ----
__global__ void __launch_bounds__(256) agg2m_csr_kernel(
        const int* __restrict__ row, const int* __restrict__ srcs,
        const float* __restrict__ a_src, const float* __restrict__ a_dst,
        const unsigned* __restrict__ hmid_u, unsigned* __restrict__ Acat_u, int N) {
    int tid = threadIdx.x;
    int d = blockIdx.x * 16 + (tid >> 4);
    if (d >= N) return;
    int q = tid & 15;
    int beg = row[d], end = row[d + 1];
    float2 adp = ((const float2*)a_dst)[d];
    float den0 = 0.f, den1 = 0.f;
    v2f a0[4], a1[4];
    #pragma unroll
    for (int m = 0; m < 4; ++m) { a0[m] = (v2f){0.f, 0.f}; a1[m] = (v2f){0.f, 0.f}; }
    for (int i = beg; i < end; i += 4) {
        bool h1 = (i + 1) < end, h2 = (i + 2) < end, h3 = (i + 3) < end;
        int s0 = srcs[i];
        int s1 = h1 ? srcs[i + 1] : s0;
        int s2 = h2 ? srcs[i + 2] : s0;
        int s3 = h3 ? srcs[i + 3] : s0;
        float2 as0 = ((const float2*)a_src)[s0];
        float2 as1 = ((const float2*)a_src)[s1];
        float2 as2 = ((const float2*)a_src)[s2];
        float2 as3 = ((const float2*)a_src)[s3];
        uint4 u0 = ((const uint4*)(hmid_u + (size_t)s0 * 64))[q];
        uint4 u1 = ((const uint4*)(hmid_u + (size_t)s1 * 64))[q];
        uint4 u2 = ((const uint4*)(hmid_u + (size_t)s2 * 64))[q];
        uint4 u3 = ((const uint4*)(hmid_u + (size_t)s3 * 64))[q];
        float e00 = __expf(lrelu(as0.x + adp.x));
        float e01 = __expf(lrelu(as0.y + adp.y));
        float e10 = h1 ? __expf(lrelu(as1.x + adp.x)) : 0.f;
        float e11 = h1 ? __expf(lrelu(as1.y + adp.y)) : 0.f;
        float e20 = h2 ? __expf(lrelu(as2.x + adp.x)) : 0.f;
        float e21 = h2 ? __expf(lrelu(as2.y + adp.y)) : 0.f;
        float e30 = h3 ? __expf(lrelu(as3.x + adp.x)) : 0.f;
        float e31 = h3 ? __expf(lrelu(as3.y + adp.y)) : 0.f;
        den0 += e00 + e10 + e20 + e30;
        den1 += e01 + e11 + e21 + e31;
        v2f p0x = bfpair(u0.x), p0y = bfpair(u0.y), p0z = bfpair(u0.z), p0w = bfpair(u0.w);
        v2f p1x = bfpair(u1.x), p1y = bfpair(u1.y), p1z = bfpair(u1.z), p1w = bfpair(u1.w);
        v2f p2x = bfpair(u2.x), p2y = bfpair(u2.y), p2z = bfpair(u2.z), p2w = bfpair(u2.w);
        v2f p3x = bfpair(u3.x), p3y = bfpair(u3.y), p3z = bfpair(u3.z), p3w = bfpair(u3.w);
        a0[0] += p0x * e00 + p1x * e10 + p2x * e20 + p3x * e30;
        a0[1] += p0y * e00 + p1y * e10 + p2y * e20 + p3y * e30;
        a0[2] += p0z * e00 + p1z * e10 + p2z * e20 + p3z * e30;
        a0[3] += p0w * e00 + p1w * e10 + p2w * e20 + p3w * e30;
        a1[0] += p0x * e01 + p1x * e11 + p2x * e21 + p3x * e31;
        a1[1] += p0y * e01 + p1y * e11 + p2y * e21 + p3y * e31;
        a1[2] += p0z * e01 + p1z * e11 + p2z * e21 + p3z * e31;
        a1[3] += p0w * e01 + p1w * e11 + p2w * e21 + p3w * e31;
    }
    float inv0 = 1.f / (den0 + 1e-16f);
    float inv1 = 1.f / (den1 + 1e-16f);
    uint4 o0, o1;
    o0.x = packbf(a0[0].x * inv0, a0[0].y * inv0);
    o0.y = packbf(a0[1].x * inv0, a0[1].y * inv0);
    o0.z = packbf(a0[2].x * inv0, a0[2].y * inv0);
    o0.w = packbf(a0[3].x * inv0, a0[3].y * inv0);
    o1.x = packbf(a1[0].x * inv1, a1[0].y * inv1);
    o1.y = packbf(a1[1].x * inv1, a1[1].y * inv1);
    o1.z = packbf(a1[2].x * inv1, a1[2].y * inv1);
    o1.w = packbf(a1[3].x * inv1, a1[3].y * inv1);
    uint4* orow = (uint4*)(Acat_u + (size_t)d * 128);
    orow[q] = o0;        // head-0 half
    orow[16 + q] = o1;   // head-1 half
}

// ---- zsd MFMA: zsd = Acat @ Wbigfrag + bz ; B staged through LDS ----
__global__ void __launch_bounds__(256) zsd_mfma_kernel(
        const __hip_bfloat16* __restrict__ Acat, const __hip_bfloat16* __restrict__ wfrag,
        const float* __restrict__ bz, __hip_bfloat16* __restrict__ zsd, int N) {
    __shared__ short sB[16384];  // 32 KB = 2 kt-groups x 16 nt x 64 lanes x 8 bf16
    int tid = threadIdx.x;
    int lane = tid & 63, wv = tid >> 6;
    int lo = lane & 15, quad = lane >> 4;
    int rowbase = (blockIdx.x * 4 + wv) * 16;   // may exceed N for tail waves; no early return (barriers)
    int arow = rowbase + lo; if (arow >= N) arow = N - 1;
    const __hip_bfloat16* ap = Acat + (size_t)arow * 256 + quad * 8;
    // preload all A fragments (8 kt x 16B = 32 VGPRs)
    short8 areg[8];
    #pragma unroll
    for (int kt = 0; kt < 8; ++kt) areg[kt] = *(const short8*)(ap + kt * 32);
    floatx4 acc[16];
    #pragma unroll
    for (int nt = 0; nt < 16; ++nt) acc[nt] = (floatx4){0.f, 0.f, 0.f, 0.f};
    const uint4* wsrc = (const uint4*)wfrag;
    #pragma unroll
    for (int stage = 0; stage < 4; ++stage) {
        // cooperative copy: 32 KB = 2048 uint4; 256 threads -> 8 iters
        const uint4* gsrc = wsrc + stage * 2048;
        #pragma unroll
        for (int it = 0; it < 8; ++it)
            ((uint4*)sB)[it * 256 + tid] = gsrc[it * 256 + tid];
        __syncthreads();
        #pragma unroll
        for (int ktl = 0; ktl < 2; ++ktl) {
            short8 a = areg[stage * 2 + ktl];
            #pragma unroll
            for (int nt = 0; nt < 16; ++nt) {
                short8 b = *(const short8*)&sB[((ktl * 16 + nt) * 64 + lane) * 8];
                acc[nt] = __builtin_amdgcn_mfma_f32_16x16x32_bf16(a, b, acc[nt], 0, 0, 0);
            }
        }
        __syncthreads();
    }
    #pragma unroll
    for (int nt = 0; nt < 16; ++nt) {
        int ch = nt * 16 + lo;
        float bv = bz[ch];
        #pragma unroll
        for (int r = 0; r < 4; ++r) {
            int row = rowbase + quad * 4 + r;
            if (row < N) ((unsigned short*)zsd)[(size_t)row * 256 + ch] = bfbits(acc[nt][r] + bv);
        }
    }
}

// ---- edge head: batched gathers (8 rounds), channel-split, shfl_xor(16) add ----
__global__ void __launch_bounds__(256) edge_zsd_kernel(
        const int* __restrict__ src, const int* __restrict__ dst,
        const unsigned* __restrict__ zsd_u, const float* __restrict__ fc3_w,
        const float* __restrict__ fc3_b, float* __restrict__ out, int E) {
    int lane = threadIdx.x & 63, wv = threadIdx.x >> 6;
    int g = lane >> 5, r = (lane >> 4) & 1, q = lane & 15;
    int base = (blockIdx.x * 4 + wv) * 16;
    if (base >= E) return;
    v2f f30 = {fc3_w[8 * q + 4 * r + 0], fc3_w[8 * q + 4 * r + 1]};
    v2f f31 = {fc3_w[8 * q + 4 * r + 2], fc3_w[8 * q + 4 * r + 3]};
    float b3 = fc3_b[0];
    int nodes[8];
    #pragma unroll
    for (int j = 0; j < 8; ++j) {
        int e = base + 2 * j + g;
        int ec = e < E ? e : E - 1;
        nodes[j] = r ? dst[ec] : src[ec];
    }
    uint4 rows[8];
    #pragma unroll
    for (int j = 0; j < 8; ++j)
        rows[j] = ((const uint4*)(zsd_u + (size_t)nodes[j] * 128 + (r << 6)))[q];
    #pragma unroll
    for (int j = 0; j < 8; ++j) {
        uint4 mine = rows[j];
        unsigned sx = (unsigned)__shfl_xor((int)mine.x, 16, 64);
        unsigned sy = (unsigned)__shfl_xor((int)mine.y, 16, 64);
        unsigned sz = (unsigned)__shfl_xor((int)mine.z, 16, 64);
        unsigned sw = (unsigned)__shfl_xor((int)mine.w, 16, 64);
        unsigned mA = r ? mine.z : mine.x;
        unsigned mB = r ? mine.w : mine.y;
        unsigned oA = r ? sz : sx;
        unsigned oB = r ? sw : sy;
        v2f sA = bfpair(mA) + bfpair(oA);
        v2f sB2 = bfpair(mB) + bfpair(oB);
        sA.x = fmaxf(sA.x, 0.f); sA.y = fmaxf(sA.y, 0.f);
        sB2.x = fmaxf(sB2.x, 0.f); sB2.y = fmaxf(sB2.y, 0.f);
        v2f p2 = sA * f30 + sB2 * f31;
        float p = p2.x + p2.y;
        #pragma unroll
        for (int off = 1; off < 32; off <<= 1) p += __shfl_xor(p, off, 64);
        int e = base + 2 * j + g;
        if ((lane & 31) == 0 && e < E)
            out[e] = 1.f / (1.f + expf(-(p + b3)));
    }
}

extern "C" void kernel_launch(void* const* d_in, const int* in_sizes, int n_in,
                              void* d_out, int out_size, void* d_ws, size_t ws_size,
                              hipStream_t stream) {
    const float* x      = (const float*)d_in[0];
    const int*   ei     = (const int*)d_in[1];
    const float* cls    = (const float*)d_in[2];
    const float* fc0_w  = (const float*)d_in[3];
    const float* fc0_b  = (const float*)d_in[4];
    const float* W1     = (const float*)d_in[5];
    const float* att_s1 = (const float*)d_in[6];
    const float* att_d1 = (const float*)d_in[7];
    const float* bias1  = (const float*)d_in[8];
    const float* W2     = (const float*)d_in[9];
    const float* att_s2 = (const float*)d_in[10];
    const float* att_d2 = (const float*)d_in[11];
    const float* bias2  = (const float*)d_in[12];
    const float* fc2_w  = (const float*)d_in[13];
    const float* fc2_b  = (const float*)d_in[14];
    const float* fc3_w  = (const float*)d_in[15];
    const float* fc3_b  = (const float*)d_in[16];
    float* out = (float*)d_out;

    int N = in_sizes[0] / 128;
    int E = in_sizes[1] / 2;
    const int* src = ei;
    const int* dst = ei + E;
    int nb = (N + 1023) / 1024;

    float* w = (float*)d_ws;
    size_t off = 0;
    auto alloc = [&](size_t n) { float* p = w + off; off += (n + 63) & ~(size_t)63; return p; };
    float* c1       = alloc(128);
    float* w1fragf  = alloc(16384 / 2);
    float* wbigf    = alloc(65536 / 2);
    float* v2s      = alloc(256);
    float* v2d      = alloc(256);
    float* bz       = alloc(256);
    float* a_s1     = alloc((size_t)N * 2);
    float* a_d1     = alloc((size_t)N * 2);
    float* a_s2     = alloc((size_t)N * 2);
    float* a_d2     = alloc((size_t)N * 2);
    float* h1bff    = alloc((size_t)N * 64);   // N*128 bf16
    float* hmidf    = alloc((size_t)N * 64);   // N*128 bf16
    float* Acatf    = alloc((size_t)N * 128);  // N*256 bf16
    float* zsdf     = alloc((size_t)N * 128);  // N*256 bf16
    int* counts = (int*)alloc(N);
    int* rowp   = (int*)alloc(N + 1);
    int* woff   = (int*)alloc(N);
    int* srcs   = (int*)alloc(E);
    int* bsum   = (int*)alloc(64);
    int* boff   = (int*)alloc(64);
    __hip_bfloat16* w1frag   = (__hip_bfloat16*)w1fragf;
    __hip_bfloat16* wbigfrag = (__hip_bfloat16*)wbigf;
    __hip_bfloat16* h1bf     = (__hip_bfloat16*)h1bff;
    __hip_bfloat16* hmid     = (__hip_bfloat16*)hmidf;
    __hip_bfloat16* Acat     = (__hip_bfloat16*)Acatf;
    __hip_bfloat16* zsd      = (__hip_bfloat16*)zsdf;

    prep_kernel<<<256, 256, 0, stream>>>(cls, fc0_w, fc0_b, W1, W2, fc2_w, fc2_b, bias2,
                                         att_s2, att_d2, c1, w1frag, wbigfrag, v2s, v2d, bz,
                                         counts, N);
    int G1 = (N + 63) / 64;
    int G2 = (E + 255) / 256;
    gemm1_count_kernel<<<G1 + G2, 256, 0, stream>>>(x, w1frag, c1, att_s1, att_d1, h1bf, a_s1, a_d1,
                                                    dst, counts, E, G1, N);
    bsum_kernel<<<nb, 256, 0, stream>>>(counts, bsum, N);
    top_scan_kernel<<<1, 64, 0, stream>>>(bsum, boff, nb);
    local_scan_kernel<<<nb, 1024, 0, stream>>>(counts, boff, rowp, woff, N, E);
    scatter_kernel<<<(E + 255) / 256, 256, 0, stream>>>(src, dst, woff, srcs, E);
    agg1_csr_kernel<<<(N + 15) / 16, 256, 0, stream>>>(rowp, srcs, a_s1, a_d1, (const unsigned*)h1bf,
                                                       bias1, v2s, v2d, (unsigned*)hmid, a_s2, a_d2, N);
    agg2m_csr_kernel<<<(N + 15) / 16, 256, 0, stream>>>(rowp, srcs, a_s2, a_d2, (const unsigned*)hmid,
                                                        (unsigned*)Acat, N);
    zsd_mfma_kernel<<<(N + 63) / 64, 256, 0, stream>>>(Acat, wbigfrag, bz, zsd, N);
    edge_zsd_kernel<<<(E + 63) / 64, 256, 0, stream>>>(src, dst, (const unsigned*)zsd, fc3_w, fc3_b, out, E);
}